// Round 12
// baseline (399.358 us; speedup 1.0000x reference)
//
#include <hip/hip_runtime.h>
#include <math.h>

#define LSEQ 36864          // 192*192
#define HH   192
#define WW   192
#define NCHK 2304           // 16-pos chunks per (b,dir) scan
#define KB_SEG 144          // chunks per kB segment (16 segments)

typedef unsigned short u16;
typedef unsigned int   u32;
typedef __bf16 bf16x8 __attribute__((ext_vector_type(8)));
typedef float  f32x4  __attribute__((ext_vector_type(4)));

#define MEMBAR() asm volatile("" ::: "memory")

// ---- workspace layout (float-unit offsets), total ~144MB ----
#define LAMRE_OFF 0
#define LAMIM_OFF 128
#define OFF_CARF  1024
#define CAR_F     2359296                 // floats per carry array (8 scans x 2304 x 64 x 2)
#define OFF_CARB  (OFF_CARF + CAR_F)
#define OFF_CINF  (OFF_CARB + CAR_F)
#define OFF_CINB  (OFF_CINF + CAR_F)
#define OFF_W     (OFF_CINB + CAR_F)      // u16 weight region
#define OFF_FX    (OFF_W + 45056)         // u16 (2dir, b, L, 64) hi-only
#define OFF_XT    (OFF_FX + 9437184)      // f32 (b, C, W, H)
#define OFF_YH    (OFF_XT + 9437184)      // u16 (b, L, 64)
#define OFF_YV    (OFF_YH + 4718592)      // u16 (b, L, 64)

// weight region layout (u16 offsets)
#define WO_BBH  0                // 2 x 128 x 64
#define WO_BBL  16384            // 2 x 128 x 64
#define WO_CC   32768            // 2 x 64 x 256
#define WO_ENC  65536            // 2 x 64 x 64
#define WO_DEC  73728            // 2 x 64 x 64
#define WO_FW   81920            // 64 x 128

__device__ __forceinline__ u16 f2b(float f) {
  __bf16 h = (__bf16)f;              // RTNE
  return *(u16*)&h;
}
__device__ __forceinline__ float b2f(u16 h) { return __uint_as_float(((u32)h) << 16); }
__device__ __forceinline__ float gelu_f(float x) {
  float t = 0.79788456080286535588f * x * (1.f + 0.044715f * x * x);
  float e = __expf(2.f * t);
  float th = 1.f - 2.f / (e + 1.f);   // tanh(t), robust at +-inf
  return 0.5f * x * (1.f + th);
}

// ---------------- k_pre: blocks 0..2303 transpose (float4), 2304..2305 setup ----------------
__global__ __launch_bounds__(256) void k_pre(
    const float* __restrict__ x, float* __restrict__ xT,
    const float* __restrict__ lam_re, const float* __restrict__ lam_im,
    const float* __restrict__ B_re, const float* __restrict__ B_im,
    const float* __restrict__ log_step,
    const float* __restrict__ C_re, const float* __restrict__ C_im,
    const float* __restrict__ ff_enc, const float* __restrict__ ff_dec,
    const float* __restrict__ fus_w,
    float* __restrict__ misc, u16* __restrict__ wreg) {
  __shared__ float t[64][65];
  const int tid = threadIdx.x, blk = blockIdx.x;
  if (blk < 2304) {
    const int bc = blk / 9, tt = blk % 9;
    const int h0 = (tt / 3) * 64, w0 = (tt % 3) * 64;
    const float4* xp4 = (const float4*)(x + (size_t)bc * HH * WW);
    float4* xq4 = (float4*)(xT + (size_t)bc * HH * WW);
#pragma unroll
    for (int k = 0; k < 4; ++k) {
      int idx = tid + k * 256; int r = idx >> 4, c4 = idx & 15;
      float4 v = xp4[(size_t)(h0 + r) * 48 + (w0 >> 2) + c4];
      t[r][c4 * 4 + 0] = v.x; t[r][c4 * 4 + 1] = v.y;
      t[r][c4 * 4 + 2] = v.z; t[r][c4 * 4 + 3] = v.w;
    }
    __syncthreads();
#pragma unroll
    for (int k = 0; k < 4; ++k) {
      int idx = tid + k * 256; int r = idx >> 4, c4 = idx & 15;
      float4 o;
      o.x = t[c4 * 4 + 0][r]; o.y = t[c4 * 4 + 1][r];
      o.z = t[c4 * 4 + 2][r]; o.w = t[c4 * 4 + 3][r];
      xq4[(size_t)(w0 + r) * 48 + (h0 >> 2) + c4] = o;
    }
    return;
  }
  const int i = blk - 2304;
  const int p = tid & 63, qq = tid >> 6;
  const float lr = lam_re[i * 64 + p], li = lam_im[i * 64 + p];
  const float dt = expf(log_step[i * 64 + p]);
  const float er = expf(lr * dt);
  const float lbr = er * cosf(li * dt), lbi = er * sinf(li * dt);
  if (qq == 0) {
    misc[LAMRE_OFF + i * 64 + p] = lbr;
    misc[LAMIM_OFF + i * 64 + p] = lbi;
  }
  const float nr = lbr - 1.f, ni = lbi;
  const float den = lr * lr + li * li;
  const float fr = (nr * lr + ni * li) / den, fi = (ni * lr - nr * li) / den;
  for (int c = qq * 16; c < qq * 16 + 16; ++c) {
    float br = B_re[i * 4096 + p * 64 + c], bi = B_im[i * 4096 + p * 64 + c];
    float wre = fr * br - fi * bi, wim = fr * bi + fi * br;
    u16 hre = f2b(wre), him = f2b(wim);
    wreg[WO_BBH + i * 8192 + p * 64 + c]        = hre;
    wreg[WO_BBH + i * 8192 + (64 + p) * 64 + c] = him;
    wreg[WO_BBL + i * 8192 + p * 64 + c]        = f2b(wre - b2f(hre));
    wreg[WO_BBL + i * 8192 + (64 + p) * 64 + c] = f2b(wim - b2f(him));
  }
  const int h = p;
  for (int pp = qq * 16; pp < qq * 16 + 16; ++pp) {
    float cr0 = C_re[i * 8192 + h * 128 + pp],      ci0 = C_im[i * 8192 + h * 128 + pp];
    float cr1 = C_re[i * 8192 + h * 128 + 64 + pp], ci1 = C_im[i * 8192 + h * 128 + 64 + pp];
    wreg[WO_CC + i * 16384 + h * 256 + pp]        = f2b( 2.f * cr0);
    wreg[WO_CC + i * 16384 + h * 256 + 64 + pp]   = f2b(-2.f * ci0);
    wreg[WO_CC + i * 16384 + h * 256 + 128 + pp]  = f2b( 2.f * cr1);
    wreg[WO_CC + i * 16384 + h * 256 + 192 + pp]  = f2b(-2.f * ci1);
  }
  for (int c = qq * 16; c < qq * 16 + 16; ++c) {
    wreg[WO_ENC + i * 4096 + p * 64 + c] = f2b(ff_enc[i * 4096 + p * 64 + c]);
    wreg[WO_DEC + i * 4096 + p * 64 + c] = f2b(ff_dec[i * 4096 + p * 64 + c]);
  }
  if (i == 0) {
    for (int k = qq * 32; k < qq * 32 + 32; ++k)
      wreg[WO_FW + p * 128 + k] = f2b(fus_w[p * 128 + k]);
  }
}

// ---------------- kA: LN1 + Bu(hi/lo MFMA) + chunk carries.  ONE barrier. ----------------
__global__ __launch_bounds__(256, 3) void kA(
    const float* __restrict__ x, const float* __restrict__ xT,
    const float* __restrict__ ln1_g, const float* __restrict__ ln1_b,
    const u16* __restrict__ wreg, const float* __restrict__ misc,
    u16* __restrict__ fxg, float2* __restrict__ carF, float2* __restrict__ carB) {
  __shared__ __align__(16) unsigned char smem[50432];
  float (*tBig)[65] = (float (*)[65])smem;                  // [0, 16640)
  const int tid = threadIdx.x, blk = blockIdx.x;
  const int dir = blk / 2304;
  const int rem = blk % 2304;
  const int bb = rem / 576, t64 = rem % 576;
  const int l0 = t64 * 64;
  const float* xin = dir ? xT : x;
  const float* g  = ln1_g + dir * 64;
  const float* be = ln1_b + dir * 64;
  const u16* BBH = wreg + WO_BBH + dir * 8192;
  const u16* BBL = wreg + WO_BBL + dir * 8192;
  const float* lre = misc + LAMRE_OFF + dir * 64;
  const float* lim = misc + LAMIM_OFF + dir * 64;

  const int lane = tid & 63, q = tid >> 6;
  const int c0 = lane & 15, gg = lane >> 4;
  const int m0 = q * 16, kb = gg * 8;
  char* wa = (char*)smem + 16640 + q * 8448;

  const float4* xp4 = (const float4*)(xin + (size_t)bb * 64 * LSEQ + l0);
#pragma unroll
  for (int k = 0; k < 4; ++k) {
    int idx = tid + k * 256; int r = idx >> 4, c4 = idx & 15;
    float4 v = xp4[(size_t)r * (LSEQ / 4) + c4];
    tBig[r][c4 * 4 + 0] = v.x; tBig[r][c4 * 4 + 1] = v.y;
    tBig[r][c4 * 4 + 2] = v.z; tBig[r][c4 * 4 + 3] = v.w;
  }
  __syncthreads();   // the ONLY barrier: tBig complete
  const int rown = m0 + c0;
  float s = 0.f, s2 = 0.f;
#pragma unroll
  for (int c = 0; c < 64; ++c) { float v = tBig[c][rown]; s += v; s2 += v * v; }
  float mu = s * (1.f / 64.f);
  float rs = rsqrtf(fmaxf(s2 * (1.f / 64.f) - mu * mu, 0.f) + 1e-5f);
  u16* fhr = (u16*)(wa + c0 * 528);
  u16* flr = (u16*)(wa + c0 * 528 + 144);
  u32 pk[8];
#pragma unroll
  for (int u = 0; u < 16; ++u) {
    int c = gg * 16 + u;
    float v = (tBig[c][rown] - mu) * rs * g[c] + be[c];
    u16 h = f2b(v);
    fhr[c] = h;
    flr[c] = f2b(v - b2f(h));
    if ((u & 1) == 0) pk[u >> 1] = (u32)h;
    else              pk[u >> 1] |= ((u32)h) << 16;
  }
  {
    u32* fx32 = (u32*)fxg + ((size_t)(dir * 4 + bb) * LSEQ + l0) * 32;
    uint4* dst = (uint4*)(fx32 + rown * 32 + gg * 8);
    uint4 p0; p0.x = pk[0]; p0.y = pk[1]; p0.z = pk[2]; p0.w = pk[3];
    uint4 p1; p1.x = pk[4]; p1.y = pk[5]; p1.z = pk[6]; p1.w = pk[7];
    dst[0] = p0; dst[1] = p1;
  }
  MEMBAR();
  const u16* fhar = (const u16*)(wa + c0 * 528);
  const u16* flar = (const u16*)(wa + c0 * 528 + 144);
  bf16x8 a0h = *(const bf16x8*)(fhar + kb);
  bf16x8 a1h = *(const bf16x8*)(fhar + 32 + kb);
  bf16x8 a0l = *(const bf16x8*)(flar + kb);
  bf16x8 a1l = *(const bf16x8*)(flar + 32 + kb);
  MEMBAR();
  f32x4 accs[8];
#pragma unroll
  for (int t = 0; t < 8; ++t) {
    const int wrow = (t * 16 + c0) * 64 + kb;
    bf16x8 b0h = *(const bf16x8*)(BBH + wrow);
    bf16x8 b1h = *(const bf16x8*)(BBH + wrow + 32);
    bf16x8 b0l = *(const bf16x8*)(BBL + wrow);
    bf16x8 b1l = *(const bf16x8*)(BBL + wrow + 32);
    f32x4 acc = {0.f, 0.f, 0.f, 0.f};
    acc = __builtin_amdgcn_mfma_f32_16x16x32_bf16(a0h, b0h, acc, 0, 0, 0);
    acc = __builtin_amdgcn_mfma_f32_16x16x32_bf16(a0l, b0h, acc, 0, 0, 0);
    acc = __builtin_amdgcn_mfma_f32_16x16x32_bf16(a0h, b0l, acc, 0, 0, 0);
    acc = __builtin_amdgcn_mfma_f32_16x16x32_bf16(a1h, b1h, acc, 0, 0, 0);
    acc = __builtin_amdgcn_mfma_f32_16x16x32_bf16(a1l, b1h, acc, 0, 0, 0);
    acc = __builtin_amdgcn_mfma_f32_16x16x32_bf16(a1h, b1l, acc, 0, 0, 0);
    accs[t] = acc;
  }
#pragma unroll
  for (int t = 0; t < 4; ++t) {
#pragma unroll
    for (int i = 0; i < 4; ++i) {
      int wr = gg * 4 + i;
      ((float*)(wa + wr * 528))[t * 16 + c0]       = accs[t][i];
      ((float*)(wa + wr * 528 + 264))[t * 16 + c0] = accs[t + 4][i];
    }
  }
  MEMBAR();
  const float Lr = lre[lane], Li = lim[lane];
  {
    float xr = 0.f, xi = 0.f;
#pragma unroll
    for (int j = 0; j < 16; ++j) {
      float br = ((const float*)(wa + j * 528))[lane];
      float bi = ((const float*)(wa + j * 528 + 264))[lane];
      float nr2 = fmaf(Lr, xr, fmaf(-Li, xi, br));
      float ni2 = fmaf(Lr, xi, fmaf( Li, xr, bi));
      xr = nr2; xi = ni2;
    }
    carF[((size_t)(dir * 4 + bb) * NCHK + t64 * 4 + q) * 64 + lane] = make_float2(xr, xi);
  }
  {
    float xr = 0.f, xi = 0.f;
#pragma unroll
    for (int j = 15; j >= 0; --j) {
      float br = ((const float*)(wa + j * 528))[lane];
      float bi = ((const float*)(wa + j * 528 + 264))[lane];
      float nr2 = fmaf(Lr, xr, fmaf(-Li, xi, br));
      float ni2 = fmaf(Lr, xi, fmaf( Li, xr, bi));
      xr = nr2; xi = ni2;
    }
    carB[((size_t)(dir * 4 + bb) * NCHK + (NCHK - 1 - (t64 * 4 + q))) * 64 + lane] = make_float2(xr, xi);
  }
}

// ---------------- kB: chunk-carry prefix over 2304 chunks (lam^16), fp64 ----------------
__global__ __launch_bounds__(1024) void kB(
    const float* __restrict__ misc,
    const float2* __restrict__ carF, const float2* __restrict__ carB,
    float2* __restrict__ cinF, float2* __restrict__ cinB) {
  __shared__ double Lwr[16][64];
  __shared__ double Lwi[16][64];
  const int ii = blockIdx.x;
  const int fb = ii & 1, sc = ii >> 1;
  const int dir = sc >> 2;
  const float2* car = fb ? carB : carF;
  float2* cin = fb ? cinB : cinF;
  const int s = threadIdx.x >> 6, p = threadIdx.x & 63;
  const double lr = (double)misc[LAMRE_OFF + dir * 64 + p];
  const double li = (double)misc[LAMIM_OFF + dir * 64 + p];
  double mr = lr, mi = li;        // lam^16 via 4 squarings (fp64)
#pragma unroll
  for (int t = 0; t < 4; ++t) { double t2 = mr * mr - mi * mi; mi = 2.0 * mr * mi; mr = t2; }
  double sr = 1.0, si = 0.0, br = mr, bi = mi;  // (lam^16)^KB_SEG
  int e = KB_SEG;
  while (e) {
    if (e & 1) { double t = sr * br - si * bi; si = sr * bi + si * br; sr = t; }
    double t2 = br * br - bi * bi; bi = 2.0 * br * bi; br = t2;
    e >>= 1;
  }
  const size_t base = ((size_t)sc * NCHK + (size_t)s * KB_SEG) * 64 + p;
  double xr = 0.0, xi = 0.0;
  for (int j = 0; j < KB_SEG; ++j) {
    float2 c = car[base + (size_t)j * 64];
    double nr = mr * xr - mi * xi + (double)c.x;
    double ni = mr * xi + mi * xr + (double)c.y;
    xr = nr; xi = ni;
  }
  Lwr[s][p] = xr; Lwi[s][p] = xi;
  __syncthreads();
  double ox = 0.0, oy = 0.0;
  for (int t = 0; t < s; ++t) {
    double nr = sr * ox - si * oy + Lwr[t][p];
    double ni = sr * oy + si * ox + Lwi[t][p];
    ox = nr; oy = ni;
  }
  xr = ox; xi = oy;
  for (int j = 0; j < KB_SEG; ++j) {
    size_t o = base + (size_t)j * 64;
    cin[o] = make_float2((float)xr, (float)xi);
    float2 c = car[o];
    double nr = mr * xr - mi * xi + (double)c.x;
    double ni = mr * xi + mi * xr + (double)c.y;
    xr = nr; xi = ni;
  }
}

// ---------------- kC tile body: zero barriers, wave-local arena ----------------
__device__ __forceinline__ void kc_tile(
    char* wa, const int lane, const int c0, const int gg, const int m0, const int kb,
    const u16* __restrict__ BBH, const u16* __restrict__ BBL, const u16* __restrict__ CC,
    const u16* __restrict__ ENC, const u16* __restrict__ DEC,
    const float Lr, const float Li,
    const float* __restrict__ Dv, const float* __restrict__ g2, const float* __restrict__ b2v,
    bf16x8 a0, bf16x8 a1, const float* ures, float2 cF, float2 cB,
    u16* __restrict__ yo, const size_t gb) {
  MEMBAR();
  // Phase B: Bu MFMA -> own-wave bu rows
  {
    f32x4 accs[8];
#pragma unroll
    for (int t = 0; t < 8; ++t) {
      const int wrow = (t * 16 + c0) * 64 + kb;
      f32x4 acc = {0.f, 0.f, 0.f, 0.f};
      acc = __builtin_amdgcn_mfma_f32_16x16x32_bf16(a0, *(const bf16x8*)(BBH + wrow), acc, 0, 0, 0);
      acc = __builtin_amdgcn_mfma_f32_16x16x32_bf16(a0, *(const bf16x8*)(BBL + wrow), acc, 0, 0, 0);
      acc = __builtin_amdgcn_mfma_f32_16x16x32_bf16(a1, *(const bf16x8*)(BBH + wrow + 32), acc, 0, 0, 0);
      acc = __builtin_amdgcn_mfma_f32_16x16x32_bf16(a1, *(const bf16x8*)(BBL + wrow + 32), acc, 0, 0, 0);
      accs[t] = acc;
    }
#pragma unroll
    for (int t = 0; t < 4; ++t) {
#pragma unroll
      for (int i = 0; i < 4; ++i) {
        int wr = gg * 4 + i;
        ((float*)(wa + wr * 528))[t * 16 + c0]       = accs[t][i];
        ((float*)(wa + wr * 528 + 264))[t * 16 + c0] = accs[t + 4][i];
      }
    }
  }
  MEMBAR();
  // Phase C: serial scans over own-wave rows (state = lane) -> packed bf16 regs
  u32 sfwd[16], sbwd[16];
  {
    float xr = cF.x, xi = cF.y;
#pragma unroll
    for (int j = 0; j < 16; ++j) {
      float br = ((const float*)(wa + j * 528))[lane];
      float bi = ((const float*)(wa + j * 528 + 264))[lane];
      float nr2 = fmaf(Lr, xr, fmaf(-Li, xi, br));
      float ni2 = fmaf(Lr, xi, fmaf( Li, xr, bi));
      xr = nr2; xi = ni2;
      sfwd[j] = (u32)f2b(xr) | ((u32)f2b(xi) << 16);
    }
    xr = cB.x; xi = cB.y;
#pragma unroll
    for (int j = 15; j >= 0; --j) {
      float br = ((const float*)(wa + j * 528))[lane];
      float bi = ((const float*)(wa + j * 528 + 264))[lane];
      float nr2 = fmaf(Lr, xr, fmaf(-Li, xi, br));
      float ni2 = fmaf(Lr, xi, fmaf( Li, xr, bi));
      xr = nr2; xi = ni2;
      sbwd[j] = (u32)f2b(xr) | ((u32)f2b(xi) << 16);
    }
  }
  MEMBAR();
  // Phase D: S writes (alias bu rows; same-wave in-order DS)
#pragma unroll
  for (int j = 0; j < 16; ++j) {
    u16* Sr = (u16*)(wa + j * 528);
    Sr[lane]       = (u16)(sfwd[j] & 0xffffu);
    Sr[64 + lane]  = (u16)(sfwd[j] >> 16);
    Sr[128 + lane] = (u16)(sbwd[j] & 0xffffu);
    Sr[192 + lane] = (u16)(sbwd[j] >> 16);
  }
  MEMBAR();
  // Phase E: proj fragments from own-wave S row
  bf16x8 a[8];
  {
    const u16* Sar = (const u16*)(wa + c0 * 528);
#pragma unroll
    for (int kk = 0; kk < 8; ++kk) a[kk] = *(const bf16x8*)(Sar + kk * 32 + kb);
  }
  MEMBAR();
  float x2v[16];
#pragma unroll
  for (int t = 0; t < 4; ++t) {
    const u16* wp = CC + (t * 16 + c0) * 256 + kb;
    f32x4 acc = {0.f, 0.f, 0.f, 0.f};
#pragma unroll
    for (int kk = 0; kk < 8; ++kk)
      acc = __builtin_amdgcn_mfma_f32_16x16x32_bf16(a[kk], *(const bf16x8*)(wp + kk * 32), acc, 0, 0, 0);
    const float dv = Dv[t * 16 + c0];
#pragma unroll
    for (int i = 0; i < 4; ++i) {
      float u = ures[t * 4 + i];
      float h = acc[i] + dv * u;
      x2v[t * 4 + i] = gelu_f(h) + u;
    }
  }
  // LN2 via 16-lane shfl groups
  float t2v[16];
  {
    float mu_[4], rsd_[4];
#pragma unroll
    for (int i = 0; i < 4; ++i) {
      float a_ = x2v[i] + x2v[4 + i] + x2v[8 + i] + x2v[12 + i];
      float b_ = x2v[i] * x2v[i] + x2v[4 + i] * x2v[4 + i] +
                 x2v[8 + i] * x2v[8 + i] + x2v[12 + i] * x2v[12 + i];
      a_ += __shfl_xor(a_, 1); b_ += __shfl_xor(b_, 1);
      a_ += __shfl_xor(a_, 2); b_ += __shfl_xor(b_, 2);
      a_ += __shfl_xor(a_, 4); b_ += __shfl_xor(b_, 4);
      a_ += __shfl_xor(a_, 8); b_ += __shfl_xor(b_, 8);
      float mu = a_ * (1.f / 64.f);
      float var = b_ * (1.f / 64.f) - mu * mu;
      mu_[i] = mu; rsd_[i] = rsqrtf(fmaxf(var, 0.f) + 1e-5f);
    }
#pragma unroll
    for (int t = 0; t < 4; ++t) {
      int col = t * 16 + c0;
      float gv = g2[col], bv = b2v[col];
#pragma unroll
      for (int i = 0; i < 4; ++i)
        t2v[t * 4 + i] = (x2v[t * 4 + i] - mu_[i]) * rsd_[i] * gv + bv;
    }
  }
  // t2 writes (alias S head; proj frag reads done)
#pragma unroll
  for (int t = 0; t < 4; ++t)
#pragma unroll
    for (int i = 0; i < 4; ++i)
      ((u16*)(wa + (gg * 4 + i) * 528))[t * 16 + c0] = f2b(t2v[t * 4 + i]);
  MEMBAR();
  // FF GEMM1
  {
    bf16x8 e0 = *(const bf16x8*)((const u16*)(wa + c0 * 528) + kb);
    bf16x8 e1 = *(const bf16x8*)((const u16*)(wa + c0 * 528) + 32 + kb);
    MEMBAR();
    f32x4 accs4[4];
#pragma unroll
    for (int t = 0; t < 4; ++t) {
      const u16* wp = ENC + (t * 16 + c0) * 64 + kb;
      f32x4 acc = {0.f, 0.f, 0.f, 0.f};
      acc = __builtin_amdgcn_mfma_f32_16x16x32_bf16(e0, *(const bf16x8*)wp, acc, 0, 0, 0);
      acc = __builtin_amdgcn_mfma_f32_16x16x32_bf16(e1, *(const bf16x8*)(wp + 32), acc, 0, 0, 0);
      accs4[t] = acc;
    }
#pragma unroll
    for (int t = 0; t < 4; ++t)
#pragma unroll
      for (int i = 0; i < 4; ++i)
        ((u16*)(wa + (gg * 4 + i) * 528 + 176))[t * 16 + c0] = f2b(accs4[t][i]);
  }
  MEMBAR();
  // FF GEMM2 + residual(regs) -> stage y in arena [304, 432)
  {
    bf16x8 d0 = *(const bf16x8*)((const u16*)(wa + c0 * 528 + 176) + kb);
    bf16x8 d1 = *(const bf16x8*)((const u16*)(wa + c0 * 528 + 176) + 32 + kb);
    MEMBAR();
#pragma unroll
    for (int t = 0; t < 4; ++t) {
      const u16* wp = DEC + (t * 16 + c0) * 64 + kb;
      f32x4 acc = {0.f, 0.f, 0.f, 0.f};
      acc = __builtin_amdgcn_mfma_f32_16x16x32_bf16(d0, *(const bf16x8*)wp, acc, 0, 0, 0);
      acc = __builtin_amdgcn_mfma_f32_16x16x32_bf16(d1, *(const bf16x8*)(wp + 32), acc, 0, 0, 0);
#pragma unroll
      for (int i = 0; i < 4; ++i)
        ((u16*)(wa + (gg * 4 + i) * 528 + 304))[t * 16 + c0] =
            f2b(acc[i] + b2f(f2b(t2v[t * 4 + i])));
    }
  }
  MEMBAR();
  // coalesced y store: lane covers 32B of its wave's 16x128B y panel
  {
    const int row = lane >> 2, seg = lane & 3;
    const u32* src = (const u32*)(wa + row * 528 + 304 + seg * 32);
    uint4 v0 = *(const uint4*)(src);
    uint4 v1 = *(const uint4*)(src + 4);
    uint4* dst = (uint4*)(yo + gb + ((size_t)(m0 + row) * 64 + seg * 16));
    dst[0] = v0; dst[1] = v1;
  }
  MEMBAR();
}

// ---------------- kC: 2 tiles per block, tile-B loads prefetched ----------------
__global__ __launch_bounds__(256, 4) void kC(
    const u16* __restrict__ fxg, const u16* __restrict__ wreg, const float* __restrict__ misc,
    const float* __restrict__ Dv_b, const float* __restrict__ g2_b, const float* __restrict__ b2_b,
    const float2* __restrict__ cinF, const float2* __restrict__ cinB,
    u16* __restrict__ yh, u16* __restrict__ yv) {
  __shared__ __align__(16) unsigned char smem[33792];
  const int tid = threadIdx.x, blk = blockIdx.x;
  const int dir = blk / 1152;
  const int rem = blk % 1152;
  const int bb = rem / 288, tg = rem % 288;
  const int t64a = tg * 2, t64b = tg * 2 + 1;
  const u16* BBH = wreg + WO_BBH + dir * 8192;
  const u16* BBL = wreg + WO_BBL + dir * 8192;
  const u16* CC  = wreg + WO_CC  + dir * 16384;
  const u16* ENC = wreg + WO_ENC + dir * 4096;
  const u16* DEC = wreg + WO_DEC + dir * 4096;
  const float* lre = misc + LAMRE_OFF + dir * 64;
  const float* lim = misc + LAMIM_OFF + dir * 64;
  const float* Dv = Dv_b + dir * 64;
  const float* g2 = g2_b + dir * 64;
  const float* b2v = b2_b + dir * 64;
  u16* yo = dir ? yv : yh;

  const int lane = tid & 63, q = tid >> 6;
  const int c0 = lane & 15, gg = lane >> 4;
  const int m0 = q * 16, kb = gg * 8;
  char* wa = (char*)smem + q * 8448;
  const float Lr = lre[lane], Li = lim[lane];
  const u16* fxbase = fxg + (size_t)(dir * 4 + bb) * LSEQ * 64;
  const size_t cchunk = (size_t)(dir * 4 + bb) * NCHK;

  // ---- all global loads for BOTH tiles issued up front ----
  const u16* rowA = fxbase + (size_t)t64a * 64 * 64;
  const u16* rowB = fxbase + (size_t)t64b * 64 * 64;
  bf16x8 a0A = *(const bf16x8*)(rowA + (size_t)(m0 + c0) * 64 + kb);
  bf16x8 a1A = *(const bf16x8*)(rowA + (size_t)(m0 + c0) * 64 + 32 + kb);
  bf16x8 a0B = *(const bf16x8*)(rowB + (size_t)(m0 + c0) * 64 + kb);
  bf16x8 a1B = *(const bf16x8*)(rowB + (size_t)(m0 + c0) * 64 + 32 + kb);
  float uresA[16], uresB[16];
#pragma unroll
  for (int t = 0; t < 4; ++t)
#pragma unroll
    for (int i = 0; i < 4; ++i) {
      uresA[t * 4 + i] = b2f(rowA[(size_t)(m0 + gg * 4 + i) * 64 + t * 16 + c0]);
      uresB[t * 4 + i] = b2f(rowB[(size_t)(m0 + gg * 4 + i) * 64 + t * 16 + c0]);
    }
  float2 cFA = cinF[(cchunk + t64a * 4 + q) * 64 + lane];
  float2 cBA = cinB[(cchunk + (NCHK - 1 - (t64a * 4 + q))) * 64 + lane];
  float2 cFB = cinF[(cchunk + t64b * 4 + q) * 64 + lane];
  float2 cBB = cinB[(cchunk + (NCHK - 1 - (t64b * 4 + q))) * 64 + lane];

  kc_tile(wa, lane, c0, gg, m0, kb, BBH, BBL, CC, ENC, DEC, Lr, Li, Dv, g2, b2v,
          a0A, a1A, uresA, cFA, cBA, yo, ((size_t)bb * LSEQ + t64a * 64) * 64);
  kc_tile(wa, lane, c0, gg, m0, kb, BBH, BBL, CC, ENC, DEC, Lr, Li, Dv, g2, b2v,
          a0B, a1B, uresB, cFB, cBB, yo, ((size_t)bb * LSEQ + t64b * 64) * 64);
}

// ---------------- fusion (MFMA K=128) ----------------
__global__ __launch_bounds__(256) void k_fusion(
    const u16* __restrict__ yh, const u16* __restrict__ yv,
    const u16* __restrict__ FWw, const float* __restrict__ bf_, float* __restrict__ out) {
  __shared__ float ot[64][65];
  const int tid = threadIdx.x, blk = blockIdx.x;
  const int bb = blk / 576;
  const int rem = blk % 576;
  const int hrow = rem / 3;
  const int w0 = (rem % 3) * 64;
  const int lane = tid & 63;
  const int m0 = (tid >> 6) * 16;
  const int wrow = w0 + m0 + (lane & 15);
  const int kb = (lane >> 4) * 8;
  const u16* ah = yh + ((size_t)bb * LSEQ + (size_t)hrow * WW + wrow) * 64 + kb;
  const u16* av = yv + ((size_t)bb * LSEQ + (size_t)wrow * HH + hrow) * 64 + kb;
  bf16x8 a[4];
  a[0] = *(const bf16x8*)ah;
  a[1] = *(const bf16x8*)(ah + 32);
  a[2] = *(const bf16x8*)av;
  a[3] = *(const bf16x8*)(av + 32);
#pragma unroll
  for (int t = 0; t < 4; ++t) {
    const u16* wp = FWw + (t * 16 + (lane & 15)) * 128 + kb;
    f32x4 acc = {0.f, 0.f, 0.f, 0.f};
#pragma unroll
    for (int kk = 0; kk < 4; ++kk)
      acc = __builtin_amdgcn_mfma_f32_16x16x32_bf16(a[kk], *(const bf16x8*)(wp + kk * 32), acc, 0, 0, 0);
    const int col = t * 16 + (lane & 15);
#pragma unroll
    for (int i = 0; i < 4; ++i) ot[col][m0 + (lane >> 4) * 4 + i] = acc[i];
  }
  __syncthreads();
#pragma unroll
  for (int k = 0; k < 16; ++k) {
    int idx = tid + k * 256; int o = idx >> 6, wi = idx & 63;
    out[(((size_t)bb * 64 + o) * HH + hrow) * WW + w0 + wi] = ot[o][wi] + bf_[o];
  }
}

extern "C" void kernel_launch(void* const* d_in, const int* in_sizes, int n_in,
                              void* d_out, int out_size, void* d_ws, size_t ws_size,
                              hipStream_t stream) {
  (void)in_sizes; (void)n_in; (void)out_size; (void)ws_size;
  const float* x       = (const float*)d_in[0];
  const float* ln1_g   = (const float*)d_in[1];
  const float* ln1_b   = (const float*)d_in[2];
  const float* lam_re  = (const float*)d_in[3];
  const float* lam_im  = (const float*)d_in[4];
  const float* B_re    = (const float*)d_in[5];
  const float* B_im    = (const float*)d_in[6];
  const float* C_re    = (const float*)d_in[7];
  const float* C_im    = (const float*)d_in[8];
  const float* Dv      = (const float*)d_in[9];
  const float* log_st  = (const float*)d_in[10];
  const float* ln2_g   = (const float*)d_in[11];
  const float* ln2_b   = (const float*)d_in[12];
  const float* ff_enc  = (const float*)d_in[13];
  const float* ff_dec  = (const float*)d_in[14];
  const float* fus_w   = (const float*)d_in[15];
  const float* fus_b   = (const float*)d_in[16];

  float*  ws    = (float*)d_ws;
  float*  misc  = ws;
  float2* carF  = (float2*)(ws + OFF_CARF);
  float2* carB  = (float2*)(ws + OFF_CARB);
  float2* cinF  = (float2*)(ws + OFF_CINF);
  float2* cinB  = (float2*)(ws + OFF_CINB);
  u16*    wreg  = (u16*)(ws + OFF_W);
  u16*    fxg   = (u16*)(ws + OFF_FX);
  float*  xT    = ws + OFF_XT;
  u16*    yh    = (u16*)(ws + OFF_YH);
  u16*    yv    = (u16*)(ws + OFF_YV);

  k_pre<<<dim3(2306), dim3(256), 0, stream>>>(
      x, xT, lam_re, lam_im, B_re, B_im, log_st, C_re, C_im,
      ff_enc, ff_dec, fus_w, misc, wreg);
  kA<<<dim3(4608), dim3(256), 0, stream>>>(
      x, xT, ln1_g, ln1_b, wreg, misc, fxg, carF, carB);
  kB<<<dim3(16), dim3(1024), 0, stream>>>(misc, carF, carB, cinF, cinB);
  kC<<<dim3(2304), dim3(256), 0, stream>>>(
      fxg, wreg, misc, Dv, ln2_g, ln2_b, cinF, cinB, yh, yv);
  k_fusion<<<dim3(2304), dim3(256), 0, stream>>>(
      yh, yv, wreg + WO_FW, fus_b, (float*)d_out);
}

// Round 13
// 217.852 us; speedup vs baseline: 1.8332x; 1.8332x over previous
//
#include <hip/hip_runtime.h>
#include <math.h>

#define LSEQ 36864          // 192*192
#define HH   192
#define WW   192
#define NCHK 2304           // 16-pos chunks per (b,dir) scan
#define KB_SEG 144          // chunks per kB segment (16 segments)

typedef unsigned short u16;
typedef unsigned int   u32;
typedef __bf16 bf16x8 __attribute__((ext_vector_type(8)));
typedef float  f32x4  __attribute__((ext_vector_type(4)));

#define MEMBAR() asm volatile("" ::: "memory")

// ---- workspace layout (float-unit offsets), total ~144MB ----
#define LAMRE_OFF 0
#define LAMIM_OFF 128
#define OFF_CARF  1024
#define CAR_F     2359296                 // floats per carry array
#define OFF_CARB  (OFF_CARF + CAR_F)
#define OFF_CINF  (OFF_CARB + CAR_F)
#define OFF_CINB  (OFF_CINF + CAR_F)
#define OFF_W     (OFF_CINB + CAR_F)      // u16 weight region (fragment-packed)
#define OFF_FX    (OFF_W + 45056)         // u16 (2dir, b, L, 64) hi-only
#define OFF_XT    (OFF_FX + 9437184)      // f32 (b, C, W, H)
#define OFF_YH    (OFF_XT + 9437184)      // u16 (b, L, 64)
#define OFF_YV    (OFF_YH + 4718592)      // u16 (b, L, 64)

// fragment-packed weight region (u16 offsets). Layout [tile][frag][lane][8]:
// BB: 8 tiles x 4 frags {b0h,b1h,b0l,b1l} x 64 lanes x 8  = 16384/dir
// CC: 4 tiles x 8 kk   x 64 x 8                            = 16384/dir
// ENC/DEC: 4 tiles x 2 halves x 64 x 8                     = 4096/dir each
// FW: 4 tiles x 4 kk x 64 x 8                              = 8192
#define WO_BB   0
#define WO_CC   32768
#define WO_ENC  65536
#define WO_DEC  73728
#define WO_FW   81920

__device__ __forceinline__ u16 f2b(float f) {
  __bf16 h = (__bf16)f;              // RTNE
  return *(u16*)&h;
}
__device__ __forceinline__ float b2f(u16 h) { return __uint_as_float(((u32)h) << 16); }
__device__ __forceinline__ float gelu_f(float x) {
  float t = 0.79788456080286535588f * x * (1.f + 0.044715f * x * x);
  float e = __expf(2.f * t);
  float th = 1.f - 2.f / (e + 1.f);   // tanh(t), robust at +-inf
  return 0.5f * x * (1.f + th);
}

// ---------------- k_pre: blocks 0..2303 transpose (float4), 2304..2305 setup ----------------
__global__ __launch_bounds__(256) void k_pre(
    const float* __restrict__ x, float* __restrict__ xT,
    const float* __restrict__ lam_re, const float* __restrict__ lam_im,
    const float* __restrict__ B_re, const float* __restrict__ B_im,
    const float* __restrict__ log_step,
    const float* __restrict__ C_re, const float* __restrict__ C_im,
    const float* __restrict__ ff_enc, const float* __restrict__ ff_dec,
    const float* __restrict__ fus_w,
    float* __restrict__ misc, u16* __restrict__ wreg) {
  __shared__ float t[64][65];
  const int tid = threadIdx.x, blk = blockIdx.x;
  if (blk < 2304) {
    const int bc = blk / 9, tt = blk % 9;
    const int h0 = (tt / 3) * 64, w0 = (tt % 3) * 64;
    const float4* xp4 = (const float4*)(x + (size_t)bc * HH * WW);
    float4* xq4 = (float4*)(xT + (size_t)bc * HH * WW);
#pragma unroll
    for (int k = 0; k < 4; ++k) {
      int idx = tid + k * 256; int r = idx >> 4, c4 = idx & 15;
      float4 v = xp4[(size_t)(h0 + r) * 48 + (w0 >> 2) + c4];
      t[r][c4 * 4 + 0] = v.x; t[r][c4 * 4 + 1] = v.y;
      t[r][c4 * 4 + 2] = v.z; t[r][c4 * 4 + 3] = v.w;
    }
    __syncthreads();
#pragma unroll
    for (int k = 0; k < 4; ++k) {
      int idx = tid + k * 256; int r = idx >> 4, c4 = idx & 15;
      float4 o;
      o.x = t[c4 * 4 + 0][r]; o.y = t[c4 * 4 + 1][r];
      o.z = t[c4 * 4 + 2][r]; o.w = t[c4 * 4 + 3][r];
      xq4[(size_t)(w0 + r) * 48 + (h0 >> 2) + c4] = o;
    }
    return;
  }
  const int i = blk - 2304;
  const int p = tid & 63, qq = tid >> 6;
  const float lr = lam_re[i * 64 + p], li = lam_im[i * 64 + p];
  const float dt = expf(log_step[i * 64 + p]);
  const float er = expf(lr * dt);
  const float lbr = er * cosf(li * dt), lbi = er * sinf(li * dt);
  if (qq == 0) {
    misc[LAMRE_OFF + i * 64 + p] = lbr;
    misc[LAMIM_OFF + i * 64 + p] = lbi;
  }
  const float nr = lbr - 1.f, ni = lbi;
  const float den = lr * lr + li * li;
  const float fr = (nr * lr + ni * li) / den, fi = (ni * lr - nr * li) / den;
  // BB: fragment-packed.  value(row r, col c) -> [t=r>>4 (+4 for im)][f=c>>5 (+2 for lo)]
  //   [lane=((c>>3)&3)*16 + (r&15)][e=c&7]
  {
    u16* bb = wreg + WO_BB + i * 16384;
    const int tre = p >> 4, tim = 4 + (p >> 4);
    for (int c = qq * 16; c < qq * 16 + 16; ++c) {
      float br = B_re[i * 4096 + p * 64 + c], bi = B_im[i * 4096 + p * 64 + c];
      float wre = fr * br - fi * bi, wim = fr * bi + fi * br;
      u16 hre = f2b(wre), him = f2b(wim);
      u16 lre_ = f2b(wre - b2f(hre)), lim_ = f2b(wim - b2f(him));
      const int fcol = c >> 5;
      const int lanep = ((c >> 3) & 3) * 16 + (p & 15);
      const int e = c & 7;
      bb[((tre * 4 + fcol) * 64 + lanep) * 8 + e]     = hre;
      bb[((tre * 4 + 2 + fcol) * 64 + lanep) * 8 + e] = lre_;
      bb[((tim * 4 + fcol) * 64 + lanep) * 8 + e]     = him;
      bb[((tim * 4 + 2 + fcol) * 64 + lanep) * 8 + e] = lim_;
    }
  }
  // CC: value(row h, k) -> [(h>>4)*8 + (k>>5)][lane=((k>>3)&3)*16+(h&15)][e=k&7]
  {
    u16* ccb = wreg + WO_CC + i * 16384;
    const int h = p;
    for (int pp = qq * 16; pp < qq * 16 + 16; ++pp) {
      float cr0 = C_re[i * 8192 + h * 128 + pp],      ci0 = C_im[i * 8192 + h * 128 + pp];
      float cr1 = C_re[i * 8192 + h * 128 + 64 + pp], ci1 = C_im[i * 8192 + h * 128 + 64 + pp];
      const float vals[4] = { 2.f * cr0, -2.f * ci0, 2.f * cr1, -2.f * ci1 };
#pragma unroll
      for (int s = 0; s < 4; ++s) {
        int k = s * 64 + pp;
        ccb[(((h >> 4) * 8 + (k >> 5)) * 64 + ((k >> 3) & 3) * 16 + (h & 15)) * 8 + (k & 7)] = f2b(vals[s]);
      }
    }
  }
  // ENC/DEC: value(row o, c) -> [(o>>4)*2 + (c>>5)][lane][e]
  {
    u16* encb = wreg + WO_ENC + i * 4096;
    u16* decb = wreg + WO_DEC + i * 4096;
    for (int c = qq * 16; c < qq * 16 + 16; ++c) {
      int idx = (((p >> 4) * 2 + (c >> 5)) * 64 + ((c >> 3) & 3) * 16 + (p & 15)) * 8 + (c & 7);
      encb[idx] = f2b(ff_enc[i * 4096 + p * 64 + c]);
      decb[idx] = f2b(ff_dec[i * 4096 + p * 64 + c]);
    }
  }
  // FW: value(row o, k) -> [(o>>4)*4 + (k>>5)][lane][e]
  if (i == 0) {
    for (int k = qq * 32; k < qq * 32 + 32; ++k) {
      int idx = (((p >> 4) * 4 + (k >> 5)) * 64 + ((k >> 3) & 3) * 16 + (p & 15)) * 8 + (k & 7);
      wreg[WO_FW + idx] = f2b(fus_w[p * 128 + k]);
    }
  }
}

// ---------------- kA: LN1 + Bu(hi/lo MFMA) + chunk carries.  ONE barrier. ----------------
__global__ __launch_bounds__(256, 3) void kA(
    const float* __restrict__ x, const float* __restrict__ xT,
    const float* __restrict__ ln1_g, const float* __restrict__ ln1_b,
    const u16* __restrict__ wreg, const float* __restrict__ misc,
    u16* __restrict__ fxg, float2* __restrict__ carF, float2* __restrict__ carB) {
  __shared__ __align__(16) unsigned char smem[50432];
  float (*tBig)[65] = (float (*)[65])smem;                  // [0, 16640)
  const int tid = threadIdx.x, blk = blockIdx.x;
  const int dir = blk / 2304;
  const int rem = blk % 2304;
  const int bb = rem / 576, t64 = rem % 576;
  const int l0 = t64 * 64;
  const float* xin = dir ? xT : x;
  const float* g  = ln1_g + dir * 64;
  const float* be = ln1_b + dir * 64;
  const u16* BBp = wreg + WO_BB + dir * 16384;
  const float* lre = misc + LAMRE_OFF + dir * 64;
  const float* lim = misc + LAMIM_OFF + dir * 64;

  const int lane = tid & 63, q = tid >> 6;
  const int c0 = lane & 15, gg = lane >> 4;
  const int m0 = q * 16, kb = gg * 8;
  char* wa = (char*)smem + 16640 + q * 8448;

  const float4* xp4 = (const float4*)(xin + (size_t)bb * 64 * LSEQ + l0);
#pragma unroll
  for (int k = 0; k < 4; ++k) {
    int idx = tid + k * 256; int r = idx >> 4, c4 = idx & 15;
    float4 v = xp4[(size_t)r * (LSEQ / 4) + c4];
    tBig[r][c4 * 4 + 0] = v.x; tBig[r][c4 * 4 + 1] = v.y;
    tBig[r][c4 * 4 + 2] = v.z; tBig[r][c4 * 4 + 3] = v.w;
  }
  __syncthreads();   // the ONLY barrier: tBig complete
  const int rown = m0 + c0;
  float s = 0.f, s2 = 0.f;
#pragma unroll
  for (int c = 0; c < 64; ++c) { float v = tBig[c][rown]; s += v; s2 += v * v; }
  float mu = s * (1.f / 64.f);
  float rs = rsqrtf(fmaxf(s2 * (1.f / 64.f) - mu * mu, 0.f) + 1e-5f);
  u16* fhr = (u16*)(wa + c0 * 528);
  u16* flr = (u16*)(wa + c0 * 528 + 144);
  u32 pk[8];
#pragma unroll
  for (int u = 0; u < 16; ++u) {
    int c = gg * 16 + u;
    float v = (tBig[c][rown] - mu) * rs * g[c] + be[c];
    u16 h = f2b(v);
    fhr[c] = h;
    flr[c] = f2b(v - b2f(h));
    if ((u & 1) == 0) pk[u >> 1] = (u32)h;
    else              pk[u >> 1] |= ((u32)h) << 16;
  }
  {
    u32* fx32 = (u32*)fxg + ((size_t)(dir * 4 + bb) * LSEQ + l0) * 32;
    uint4* dst = (uint4*)(fx32 + rown * 32 + gg * 8);
    uint4 p0; p0.x = pk[0]; p0.y = pk[1]; p0.z = pk[2]; p0.w = pk[3];
    uint4 p1; p1.x = pk[4]; p1.y = pk[5]; p1.z = pk[6]; p1.w = pk[7];
    dst[0] = p0; dst[1] = p1;
  }
  MEMBAR();
  const u16* fhar = (const u16*)(wa + c0 * 528);
  const u16* flar = (const u16*)(wa + c0 * 528 + 144);
  bf16x8 a0h = *(const bf16x8*)(fhar + kb);
  bf16x8 a1h = *(const bf16x8*)(fhar + 32 + kb);
  bf16x8 a0l = *(const bf16x8*)(flar + kb);
  bf16x8 a1l = *(const bf16x8*)(flar + 32 + kb);
  MEMBAR();
  f32x4 accs[8];
#pragma unroll
  for (int t = 0; t < 8; ++t) {
    const u16* bp = BBp + (size_t)(t * 4 * 64 + lane) * 8;   // [t][f][lane][8]
    bf16x8 b0h = *(const bf16x8*)(bp);
    bf16x8 b1h = *(const bf16x8*)(bp + 512);
    bf16x8 b0l = *(const bf16x8*)(bp + 1024);
    bf16x8 b1l = *(const bf16x8*)(bp + 1536);
    f32x4 acc = {0.f, 0.f, 0.f, 0.f};
    acc = __builtin_amdgcn_mfma_f32_16x16x32_bf16(a0h, b0h, acc, 0, 0, 0);
    acc = __builtin_amdgcn_mfma_f32_16x16x32_bf16(a0l, b0h, acc, 0, 0, 0);
    acc = __builtin_amdgcn_mfma_f32_16x16x32_bf16(a0h, b0l, acc, 0, 0, 0);
    acc = __builtin_amdgcn_mfma_f32_16x16x32_bf16(a1h, b1h, acc, 0, 0, 0);
    acc = __builtin_amdgcn_mfma_f32_16x16x32_bf16(a1l, b1h, acc, 0, 0, 0);
    acc = __builtin_amdgcn_mfma_f32_16x16x32_bf16(a1h, b1l, acc, 0, 0, 0);
    accs[t] = acc;
  }
#pragma unroll
  for (int t = 0; t < 4; ++t) {
#pragma unroll
    for (int i = 0; i < 4; ++i) {
      int wr = gg * 4 + i;
      ((float*)(wa + wr * 528))[t * 16 + c0]       = accs[t][i];
      ((float*)(wa + wr * 528 + 264))[t * 16 + c0] = accs[t + 4][i];
    }
  }
  MEMBAR();
  const float Lr = lre[lane], Li = lim[lane];
  {
    float xr = 0.f, xi = 0.f;
#pragma unroll
    for (int j = 0; j < 16; ++j) {
      float br = ((const float*)(wa + j * 528))[lane];
      float bi = ((const float*)(wa + j * 528 + 264))[lane];
      float nr2 = fmaf(Lr, xr, fmaf(-Li, xi, br));
      float ni2 = fmaf(Lr, xi, fmaf( Li, xr, bi));
      xr = nr2; xi = ni2;
    }
    carF[((size_t)(dir * 4 + bb) * NCHK + t64 * 4 + q) * 64 + lane] = make_float2(xr, xi);
  }
  {
    float xr = 0.f, xi = 0.f;
#pragma unroll
    for (int j = 15; j >= 0; --j) {
      float br = ((const float*)(wa + j * 528))[lane];
      float bi = ((const float*)(wa + j * 528 + 264))[lane];
      float nr2 = fmaf(Lr, xr, fmaf(-Li, xi, br));
      float ni2 = fmaf(Lr, xi, fmaf( Li, xr, bi));
      xr = nr2; xi = ni2;
    }
    carB[((size_t)(dir * 4 + bb) * NCHK + (NCHK - 1 - (t64 * 4 + q))) * 64 + lane] = make_float2(xr, xi);
  }
}

// ---------------- kB: chunk-carry prefix over 2304 chunks (lam^16), fp64 ----------------
__global__ __launch_bounds__(1024) void kB(
    const float* __restrict__ misc,
    const float2* __restrict__ carF, const float2* __restrict__ carB,
    float2* __restrict__ cinF, float2* __restrict__ cinB) {
  __shared__ double Lwr[16][64];
  __shared__ double Lwi[16][64];
  const int ii = blockIdx.x;
  const int fb = ii & 1, sc = ii >> 1;
  const int dir = sc >> 2;
  const float2* car = fb ? carB : carF;
  float2* cin = fb ? cinB : cinF;
  const int s = threadIdx.x >> 6, p = threadIdx.x & 63;
  const double lr = (double)misc[LAMRE_OFF + dir * 64 + p];
  const double li = (double)misc[LAMIM_OFF + dir * 64 + p];
  double mr = lr, mi = li;        // lam^16 via 4 squarings (fp64)
#pragma unroll
  for (int t = 0; t < 4; ++t) { double t2 = mr * mr - mi * mi; mi = 2.0 * mr * mi; mr = t2; }
  double sr = 1.0, si = 0.0, br = mr, bi = mi;  // (lam^16)^KB_SEG
  int e = KB_SEG;
  while (e) {
    if (e & 1) { double t = sr * br - si * bi; si = sr * bi + si * br; sr = t; }
    double t2 = br * br - bi * bi; bi = 2.0 * br * bi; br = t2;
    e >>= 1;
  }
  const size_t base = ((size_t)sc * NCHK + (size_t)s * KB_SEG) * 64 + p;
  double xr = 0.0, xi = 0.0;
  for (int j = 0; j < KB_SEG; ++j) {
    float2 c = car[base + (size_t)j * 64];
    double nr = mr * xr - mi * xi + (double)c.x;
    double ni = mr * xi + mi * xr + (double)c.y;
    xr = nr; xi = ni;
  }
  Lwr[s][p] = xr; Lwi[s][p] = xi;
  __syncthreads();
  double ox = 0.0, oy = 0.0;
  for (int t = 0; t < s; ++t) {
    double nr = sr * ox - si * oy + Lwr[t][p];
    double ni = sr * oy + si * ox + Lwi[t][p];
    ox = nr; oy = ni;
  }
  xr = ox; xi = oy;
  for (int j = 0; j < KB_SEG; ++j) {
    size_t o = base + (size_t)j * 64;
    cin[o] = make_float2((float)xr, (float)xi);
    float2 c = car[o];
    double nr = mr * xr - mi * xi + (double)c.x;
    double ni = mr * xi + mi * xr + (double)c.y;
    xr = nr; xi = ni;
  }
}

// ---------------- kC: ZERO barriers, wave-local arena, fragment-packed weights ----------------
__global__ __launch_bounds__(256, 4) void kC(
    const u16* __restrict__ fxg, const u16* __restrict__ wreg, const float* __restrict__ misc,
    const float* __restrict__ Dv_b, const float* __restrict__ g2_b, const float* __restrict__ b2_b,
    const float2* __restrict__ cinF, const float2* __restrict__ cinB,
    u16* __restrict__ yh, u16* __restrict__ yv) {
  __shared__ __align__(16) unsigned char smem[33792];
  const int tid = threadIdx.x, blk = blockIdx.x;
  const int dir = blk / 2304;
  const int rem = blk % 2304;
  const int bb = rem / 576, t64 = rem % 576;
  const int l0 = t64 * 64;
  const u16* BBp = wreg + WO_BB + dir * 16384;
  const u16* CCp = wreg + WO_CC + dir * 16384;
  const u16* ENCp = wreg + WO_ENC + dir * 4096;
  const u16* DECp = wreg + WO_DEC + dir * 4096;
  const float* lre = misc + LAMRE_OFF + dir * 64;
  const float* lim = misc + LAMIM_OFF + dir * 64;
  const float* Dv = Dv_b + dir * 64;
  const float* g2 = g2_b + dir * 64;
  const float* b2v = b2_b + dir * 64;
  u16* yo = dir ? yv : yh;

  const int lane = tid & 63, q = tid >> 6;
  const int c0 = lane & 15, gg = lane >> 4;
  const int m0 = q * 16, kb = gg * 8;
  char* wa = (char*)smem + q * 8448;
  const size_t gb = ((size_t)bb * LSEQ + l0) * 64;

  // Phase A: global loads (A-frags, residual u, cin)
  const u16* fxrow = fxg + ((size_t)(dir * 4 + bb) * LSEQ + l0) * 64;
  bf16x8 a0 = *(const bf16x8*)(fxrow + (size_t)(m0 + c0) * 64 + kb);
  bf16x8 a1 = *(const bf16x8*)(fxrow + (size_t)(m0 + c0) * 64 + 32 + kb);
  float ures[16];
#pragma unroll
  for (int t = 0; t < 4; ++t)
#pragma unroll
    for (int i = 0; i < 4; ++i)
      ures[t * 4 + i] = b2f(fxrow[(size_t)(m0 + gg * 4 + i) * 64 + t * 16 + c0]);
  float2 cF = cinF[((size_t)(dir * 4 + bb) * NCHK + t64 * 4 + q) * 64 + lane];
  float2 cB = cinB[((size_t)(dir * 4 + bb) * NCHK + (NCHK - 1 - (t64 * 4 + q))) * 64 + lane];
  // Phase B: Bu MFMA -> own-wave bu rows (packed weight loads: contiguous 1KB/wave)
  {
    f32x4 accs[8];
#pragma unroll
    for (int t = 0; t < 8; ++t) {
      const u16* bp = BBp + (size_t)(t * 4 * 64 + lane) * 8;
      bf16x8 b0h = *(const bf16x8*)(bp);
      bf16x8 b1h = *(const bf16x8*)(bp + 512);
      bf16x8 b0l = *(const bf16x8*)(bp + 1024);
      bf16x8 b1l = *(const bf16x8*)(bp + 1536);
      f32x4 acc = {0.f, 0.f, 0.f, 0.f};
      acc = __builtin_amdgcn_mfma_f32_16x16x32_bf16(a0, b0h, acc, 0, 0, 0);
      acc = __builtin_amdgcn_mfma_f32_16x16x32_bf16(a0, b0l, acc, 0, 0, 0);
      acc = __builtin_amdgcn_mfma_f32_16x16x32_bf16(a1, b1h, acc, 0, 0, 0);
      acc = __builtin_amdgcn_mfma_f32_16x16x32_bf16(a1, b1l, acc, 0, 0, 0);
      accs[t] = acc;
    }
#pragma unroll
    for (int t = 0; t < 4; ++t) {
#pragma unroll
      for (int i = 0; i < 4; ++i) {
        int wr = gg * 4 + i;
        ((float*)(wa + wr * 528))[t * 16 + c0]       = accs[t][i];
        ((float*)(wa + wr * 528 + 264))[t * 16 + c0] = accs[t + 4][i];
      }
    }
  }
  MEMBAR();
  // Phase C: serial scans over own-wave rows (state = lane) -> packed bf16 regs
  u32 sfwd[16], sbwd[16];
  {
    const float Lr = lre[lane], Li = lim[lane];
    float xr = cF.x, xi = cF.y;
#pragma unroll
    for (int j = 0; j < 16; ++j) {
      float br = ((const float*)(wa + j * 528))[lane];
      float bi = ((const float*)(wa + j * 528 + 264))[lane];
      float nr2 = fmaf(Lr, xr, fmaf(-Li, xi, br));
      float ni2 = fmaf(Lr, xi, fmaf( Li, xr, bi));
      xr = nr2; xi = ni2;
      sfwd[j] = (u32)f2b(xr) | ((u32)f2b(xi) << 16);
    }
    xr = cB.x; xi = cB.y;
#pragma unroll
    for (int j = 15; j >= 0; --j) {
      float br = ((const float*)(wa + j * 528))[lane];
      float bi = ((const float*)(wa + j * 528 + 264))[lane];
      float nr2 = fmaf(Lr, xr, fmaf(-Li, xi, br));
      float ni2 = fmaf(Lr, xi, fmaf( Li, xr, bi));
      xr = nr2; xi = ni2;
      sbwd[j] = (u32)f2b(xr) | ((u32)f2b(xi) << 16);
    }
  }
  MEMBAR();
  // Phase D: S writes (alias bu rows; same-wave in-order DS)
#pragma unroll
  for (int j = 0; j < 16; ++j) {
    u16* Sr = (u16*)(wa + j * 528);
    Sr[lane]       = (u16)(sfwd[j] & 0xffffu);
    Sr[64 + lane]  = (u16)(sfwd[j] >> 16);
    Sr[128 + lane] = (u16)(sbwd[j] & 0xffffu);
    Sr[192 + lane] = (u16)(sbwd[j] >> 16);
  }
  MEMBAR();
  // Phase E: proj fragments from own-wave S row
  bf16x8 a[8];
  {
    const u16* Sar = (const u16*)(wa + c0 * 528);
#pragma unroll
    for (int kk = 0; kk < 8; ++kk) a[kk] = *(const bf16x8*)(Sar + kk * 32 + kb);
  }
  MEMBAR();
  float x2v[16];
#pragma unroll
  for (int t = 0; t < 4; ++t) {
    f32x4 acc = {0.f, 0.f, 0.f, 0.f};
#pragma unroll
    for (int kk = 0; kk < 8; ++kk)
      acc = __builtin_amdgcn_mfma_f32_16x16x32_bf16(
          a[kk], *(const bf16x8*)(CCp + (size_t)((t * 8 + kk) * 64 + lane) * 8), acc, 0, 0, 0);
    const float dv = Dv[t * 16 + c0];
#pragma unroll
    for (int i = 0; i < 4; ++i) {
      float u = ures[t * 4 + i];
      float h = acc[i] + dv * u;
      x2v[t * 4 + i] = gelu_f(h) + u;
    }
  }
  // LN2 via 16-lane shfl groups
  float t2v[16];
  {
    float mu_[4], rsd_[4];
#pragma unroll
    for (int i = 0; i < 4; ++i) {
      float a_ = x2v[i] + x2v[4 + i] + x2v[8 + i] + x2v[12 + i];
      float b_ = x2v[i] * x2v[i] + x2v[4 + i] * x2v[4 + i] +
                 x2v[8 + i] * x2v[8 + i] + x2v[12 + i] * x2v[12 + i];
      a_ += __shfl_xor(a_, 1); b_ += __shfl_xor(b_, 1);
      a_ += __shfl_xor(a_, 2); b_ += __shfl_xor(b_, 2);
      a_ += __shfl_xor(a_, 4); b_ += __shfl_xor(b_, 4);
      a_ += __shfl_xor(a_, 8); b_ += __shfl_xor(b_, 8);
      float mu = a_ * (1.f / 64.f);
      float var = b_ * (1.f / 64.f) - mu * mu;
      mu_[i] = mu; rsd_[i] = rsqrtf(fmaxf(var, 0.f) + 1e-5f);
    }
#pragma unroll
    for (int t = 0; t < 4; ++t) {
      int col = t * 16 + c0;
      float gv = g2[col], bv = b2v[col];
#pragma unroll
      for (int i = 0; i < 4; ++i)
        t2v[t * 4 + i] = (x2v[t * 4 + i] - mu_[i]) * rsd_[i] * gv + bv;
    }
  }
  // t2 writes (alias S head; proj frag reads done)
#pragma unroll
  for (int t = 0; t < 4; ++t)
#pragma unroll
    for (int i = 0; i < 4; ++i)
      ((u16*)(wa + (gg * 4 + i) * 528))[t * 16 + c0] = f2b(t2v[t * 4 + i]);
  MEMBAR();
  // FF GEMM1 (fragments from own-wave t2 row; packed ENC)
  {
    bf16x8 e0 = *(const bf16x8*)((const u16*)(wa + c0 * 528) + kb);
    bf16x8 e1 = *(const bf16x8*)((const u16*)(wa + c0 * 528) + 32 + kb);
    MEMBAR();
    f32x4 accs4[4];
#pragma unroll
    for (int t = 0; t < 4; ++t) {
      const u16* wp = ENCp + (size_t)(t * 2 * 64 + lane) * 8;
      f32x4 acc = {0.f, 0.f, 0.f, 0.f};
      acc = __builtin_amdgcn_mfma_f32_16x16x32_bf16(e0, *(const bf16x8*)wp, acc, 0, 0, 0);
      acc = __builtin_amdgcn_mfma_f32_16x16x32_bf16(e1, *(const bf16x8*)(wp + 512), acc, 0, 0, 0);
      accs4[t] = acc;
    }
#pragma unroll
    for (int t = 0; t < 4; ++t)
#pragma unroll
      for (int i = 0; i < 4; ++i)
        ((u16*)(wa + (gg * 4 + i) * 528 + 176))[t * 16 + c0] = f2b(accs4[t][i]);
  }
  MEMBAR();
  // FF GEMM2 + residual(regs) -> y (packed DEC)
  {
    bf16x8 d0 = *(const bf16x8*)((const u16*)(wa + c0 * 528 + 176) + kb);
    bf16x8 d1 = *(const bf16x8*)((const u16*)(wa + c0 * 528 + 176) + 32 + kb);
    MEMBAR();
#pragma unroll
    for (int t = 0; t < 4; ++t) {
      const u16* wp = DECp + (size_t)(t * 2 * 64 + lane) * 8;
      f32x4 acc = {0.f, 0.f, 0.f, 0.f};
      acc = __builtin_amdgcn_mfma_f32_16x16x32_bf16(d0, *(const bf16x8*)wp, acc, 0, 0, 0);
      acc = __builtin_amdgcn_mfma_f32_16x16x32_bf16(d1, *(const bf16x8*)(wp + 512), acc, 0, 0, 0);
#pragma unroll
      for (int i = 0; i < 4; ++i) {
        int row = m0 + gg * 4 + i;
        int col = t * 16 + c0;
        yo[gb + (size_t)row * 64 + col] = f2b(acc[i] + b2f(f2b(t2v[t * 4 + i])));
      }
    }
  }
}

// ---------------- fusion (MFMA K=128, packed FW) ----------------
__global__ __launch_bounds__(256) void k_fusion(
    const u16* __restrict__ yh, const u16* __restrict__ yv,
    const u16* __restrict__ FWp, const float* __restrict__ bf_, float* __restrict__ out) {
  __shared__ float ot[64][65];
  const int tid = threadIdx.x, blk = blockIdx.x;
  const int bb = blk / 576;
  const int rem = blk % 576;
  const int hrow = rem / 3;
  const int w0 = (rem % 3) * 64;
  const int lane = tid & 63;
  const int m0 = (tid >> 6) * 16;
  const int wrow = w0 + m0 + (lane & 15);
  const int kb = (lane >> 4) * 8;
  const u16* ah = yh + ((size_t)bb * LSEQ + (size_t)hrow * WW + wrow) * 64 + kb;
  const u16* av = yv + ((size_t)bb * LSEQ + (size_t)wrow * HH + hrow) * 64 + kb;
  bf16x8 a[4];
  a[0] = *(const bf16x8*)ah;
  a[1] = *(const bf16x8*)(ah + 32);
  a[2] = *(const bf16x8*)av;
  a[3] = *(const bf16x8*)(av + 32);
#pragma unroll
  for (int t = 0; t < 4; ++t) {
    f32x4 acc = {0.f, 0.f, 0.f, 0.f};
#pragma unroll
    for (int kk = 0; kk < 4; ++kk)
      acc = __builtin_amdgcn_mfma_f32_16x16x32_bf16(
          a[kk], *(const bf16x8*)(FWp + (size_t)((t * 4 + kk) * 64 + lane) * 8), acc, 0, 0, 0);
    const int col = t * 16 + (lane & 15);
#pragma unroll
    for (int i = 0; i < 4; ++i) ot[col][m0 + (lane >> 4) * 4 + i] = acc[i];
  }
  __syncthreads();
#pragma unroll
  for (int k = 0; k < 16; ++k) {
    int idx = tid + k * 256; int o = idx >> 6, wi = idx & 63;
    out[(((size_t)bb * 64 + o) * HH + hrow) * WW + w0 + wi] = ot[o][wi] + bf_[o];
  }
}

extern "C" void kernel_launch(void* const* d_in, const int* in_sizes, int n_in,
                              void* d_out, int out_size, void* d_ws, size_t ws_size,
                              hipStream_t stream) {
  (void)in_sizes; (void)n_in; (void)out_size; (void)ws_size;
  const float* x       = (const float*)d_in[0];
  const float* ln1_g   = (const float*)d_in[1];
  const float* ln1_b   = (const float*)d_in[2];
  const float* lam_re  = (const float*)d_in[3];
  const float* lam_im  = (const float*)d_in[4];
  const float* B_re    = (const float*)d_in[5];
  const float* B_im    = (const float*)d_in[6];
  const float* C_re    = (const float*)d_in[7];
  const float* C_im    = (const float*)d_in[8];
  const float* Dv      = (const float*)d_in[9];
  const float* log_st  = (const float*)d_in[10];
  const float* ln2_g   = (const float*)d_in[11];
  const float* ln2_b   = (const float*)d_in[12];
  const float* ff_enc  = (const float*)d_in[13];
  const float* ff_dec  = (const float*)d_in[14];
  const float* fus_w   = (const float*)d_in[15];
  const float* fus_b   = (const float*)d_in[16];

  float*  ws    = (float*)d_ws;
  float*  misc  = ws;
  float2* carF  = (float2*)(ws + OFF_CARF);
  float2* carB  = (float2*)(ws + OFF_CARB);
  float2* cinF  = (float2*)(ws + OFF_CINF);
  float2* cinB  = (float2*)(ws + OFF_CINB);
  u16*    wreg  = (u16*)(ws + OFF_W);
  u16*    fxg   = (u16*)(ws + OFF_FX);
  float*  xT    = ws + OFF_XT;
  u16*    yh    = (u16*)(ws + OFF_YH);
  u16*    yv    = (u16*)(ws + OFF_YV);

  k_pre<<<dim3(2306), dim3(256), 0, stream>>>(
      x, xT, lam_re, lam_im, B_re, B_im, log_st, C_re, C_im,
      ff_enc, ff_dec, fus_w, misc, wreg);
  kA<<<dim3(4608), dim3(256), 0, stream>>>(
      x, xT, ln1_g, ln1_b, wreg, misc, fxg, carF, carB);
  kB<<<dim3(16), dim3(1024), 0, stream>>>(misc, carF, carB, cinF, cinB);
  kC<<<dim3(4608), dim3(256), 0, stream>>>(
      fxg, wreg, misc, Dv, ln2_g, ln2_b, cinF, cinB, yh, yv);
  k_fusion<<<dim3(2304), dim3(256), 0, stream>>>(
      yh, yv, wreg + WO_FW, fus_b, (float*)d_out);
}